// Round 12
// baseline (256.523 us; speedup 1.0000x reference)
//
#include <hip/hip_runtime.h>
#include <math.h>

#define NB 8
#define NC 3
#define NH 1024
#define NW 1024
#define EPS 1e-6f

#define BAND 128            // output cols per wave (float2 per lane)
#define CH 32               // output rows per wave
#define KSTEPS (CH + 10)    // 42 product rows per chunk
#define PADW 144            // 8 pad | 128 | 8 pad  (floats)
#define NLD 36              // load lanes: 36 x float4 = 144 floats per row
// grid: 8 batches * 8 bands * 32 chunks = 2048 blocks of 64 threads (1 wave).
// vs R11 (same skeleton: parity LDS dbuf, single RAW barrier, 2-deep rotate):
// load front-end reshaped to 36-lane float4 -- issued bytes/step 6144->3456
// (R2/R11 issued-logical ran at 5.7 TB/s ~ 90% of copy ceiling; 44% of the
// old issue was 56 lanes broadcasting clamped garbage at offset 0).

__global__ __launch_bounds__(64, 2)
void lcs_kernel(const float* __restrict__ x, const float* __restrict__ y,
                float* __restrict__ out) {
    __shared__ __align__(16) float P[2][3][PADW];   // 3456 B, parity-buffered

    const int l   = threadIdx.x;                 // 0..63
    const int bid = blockIdx.x;
    const int b     = bid >> 8;                  // scalar (blockIdx-derived)
    const int rem   = bid & 255;
    const int band0 = (rem & 7) * BAND;
    const int r0    = (rem >> 3) * CH;

    const size_t chan = (size_t)NH * NW;
    const float* xb = x + (size_t)b * NC * chan;
    const float* yb = y + (size_t)b * NC * chan;

    // load-lane geometry: lane i<36 owns cols c0..c0+3 of the 144-wide band
    const int c0 = band0 - 8 + 4 * l;
    const bool lv = (l < NLD) && (c0 >= 0) && (c0 + 3 <= NW - 1);
    const float cm = lv ? 1.f : 0.f;             // col-block validity mask
    const int oc = lv ? c0 : 0;                  // clamped -> always in-row

    float4 cur[6], nx1[6], nx2[6];
    // d[0..2] = x ch0..2, d[3..5] = y ch0..2 (lane's 4 cols, all channels)
    auto ldrow = [&](int gr, float4* d) {
        const int rc = gr < 0 ? 0 : (gr > NH - 1 ? NH - 1 : gr);   // scalar clamp
        const size_t ro = (size_t)rc * NW;
        if (l < NLD) {                           // exec-masked: 36 lanes issue
            #pragma unroll
            for (int c = 0; c < 3; ++c) {
                d[c]     = *(const float4*)(xb + c * chan + ro + oc);
                d[3 + c] = *(const float4*)(yb + c * chan + ro + oc);
            }
        }
    };

    ldrow(r0 - 5, cur);   // prime k=0
    ldrow(r0 - 4, nx1);   // prime k=1

    float2 ring[3][11];
    #pragma unroll
    for (int p = 0; p < 3; ++p)
        #pragma unroll
        for (int s = 0; s < 11; ++s) ring[p][s] = make_float2(0.f, 0.f);
    float2 vs[3] = {make_float2(0.f,0.f), make_float2(0.f,0.f), make_float2(0.f,0.f)};

    for (int g = 0; g < 4; ++g) {                 // rolled (code stays ~11 steps)
        const int gg = g & 1;                     // k parity = (g&1)^(s&1), 11 odd
        #pragma unroll
        for (int s = 0; s < 11; ++s) {            // unrolled -> static ring index
            const int k = g * 11 + s;
            if (k >= KSTEPS) continue;            // uniform, only g==3,s>=9

            // ---- prefetch row k+2 ----
            if (k + 2 < KSTEPS) ldrow(r0 - 3 + k, nx2);

            // ---- channel-reduced products (lane's 4 cols), masked ----
            const int gr = r0 - 5 + k;
            const float rmf = (gr >= 0 && gr < NH) ? 1.f : 0.f;   // scalar
            const float cmr = rmf * cm;

            float4 pxx = make_float4(0.f,0.f,0.f,0.f), pyy = pxx, pxy = pxx;
            #pragma unroll
            for (int c = 0; c < 3; ++c) {
                const float4 fx = cur[c], fy = cur[3 + c];
                pxx.x += fx.x*fx.x; pxx.y += fx.y*fx.y; pxx.z += fx.z*fx.z; pxx.w += fx.w*fx.w;
                pyy.x += fy.x*fy.x; pyy.y += fy.y*fy.y; pyy.z += fy.z*fy.z; pyy.w += fy.w*fy.w;
                pxy.x += fx.x*fy.x; pxy.y += fx.y*fy.y; pxy.z += fx.z*fy.z; pxy.w += fx.w*fy.w;
            }
            pxx.x *= cmr; pxx.y *= cmr; pxx.z *= cmr; pxx.w *= cmr;
            pyy.x *= cmr; pyy.y *= cmr; pyy.z *= cmr; pyy.w *= cmr;
            pxy.x *= cmr; pxy.y *= cmr; pxy.z *= cmr; pxy.w *= cmr;

            // parity-selected LDS buffer; step s+1 writes the OTHER buffer
            const int pp = gg ^ (s & 1);
            float* Pb = &P[pp][0][0];

            if (l < NLD) {                        // 36 x ds_write_b128 = 144 floats
                *(float4*)(Pb + 0*PADW + 4*l) = pxx;
                *(float4*)(Pb + 1*PADW + 4*l) = pyy;
                *(float4*)(Pb + 2*PADW + 4*l) = pxy;
            }
            __builtin_amdgcn_wave_barrier();   // REQUIRED: cross-lane RAW fence

            // ---- horizontal 11-tap + vertical running sum (ring) ----
            #pragma unroll
            for (int p = 0; p < 3; ++p) {
                const float* Pq = Pb + p * PADW;
                float2 t[7];
                #pragma unroll
                for (int j = 0; j < 7; ++j)
                    t[j] = *(const float2*)(Pq + 2*l + 2 + 2*j);
                float h0 = ((t[0].y + t[1].x) + (t[1].y + t[2].x))
                         + ((t[2].y + t[3].x) + (t[3].y + t[4].x))
                         + ((t[4].y + t[5].x) + t[5].y);
                float h1 = h0 - t[0].y + t[6].x;
                vs[p].x += h0 - ring[p][s].x;
                vs[p].y += h1 - ring[p][s].y;
                ring[p][s].x = h0;
                ring[p][s].y = h1;
            }

            // ---- emit ----
            if (k >= 10) {
                const int orow = r0 + k - 10;
                const float d0 = __builtin_amdgcn_sqrtf(vs[0].x) *
                                 __builtin_amdgcn_sqrtf(vs[1].x) + EPS;
                const float d1 = __builtin_amdgcn_sqrtf(vs[0].y) *
                                 __builtin_amdgcn_sqrtf(vs[1].y) + EPS;
                float2 o;
                o.x = vs[2].x * __builtin_amdgcn_rcpf(d0);
                o.y = vs[2].y * __builtin_amdgcn_rcpf(d1);
                *(float2*)(out + ((size_t)b * NH + orow) * NW + band0 + 2*l) = o;
            }

            // rotate pipeline (renamed across unrolled copies)
            if (k + 1 < KSTEPS) {
                #pragma unroll
                for (int i = 0; i < 6; ++i) { cur[i] = nx1[i]; nx1[i] = nx2[i]; }
            }
        }
    }
}

extern "C" void kernel_launch(void* const* d_in, const int* in_sizes, int n_in,
                              void* d_out, int out_size, void* d_ws, size_t ws_size,
                              hipStream_t stream) {
    const float* x = (const float*)d_in[0];
    const float* y = (const float*)d_in[1];
    float* out = (float*)d_out;
    lcs_kernel<<<dim3(2048), dim3(64), 0, stream>>>(x, y, out);
}